// Round 4
// baseline (4072.530 us; speedup 1.0000x reference)
//
#include <hip/hip_runtime.h>
#include <hip/hip_bf16.h>
#include <math.h>

// Problem constants
#define N_B    256   // batch
#define L_SEQ  512   // sequence length
#define HID    512   // hidden
#define EMB_D  256   // embedding dim

// Decomposition: 16 groups x 16 batch rows; 8 wgs per group, each owns a
// 64-col slice of Whh (hi/lo bf16 in registers) AND the matching 64-col slice
// of Wxh. xp_t is computed on the fly (no XP workspace; ws_size can't hold
// fp32 XP — R3 aborted on the 268 MB allocation).
#define NGROUPS 16
#define GWGS    8
#define FLAG_STRIDE 16   // ints; 64B per flag to avoid line sharing

// Workspace layout (bytes): exchange + flags only (~1.1 MB)
#define EX_WORDS_PER_GROUP (16 * HID)                        // 8192 uints = 32KB
#define EX_BYTES  ((size_t)2 * NGROUPS * EX_WORDS_PER_GROUP * 4)  // 1 MB (dbuf)
#define FLAG_BYTES ((size_t)NGROUPS * GWGS * FLAG_STRIDE * 4)

typedef short v8s __attribute__((ext_vector_type(8)));   // 8 bf16 MFMA A/B frag
typedef float v4f __attribute__((ext_vector_type(4)));   // MFMA C/D frag

static __device__ __forceinline__ unsigned short bf_bits(__hip_bfloat16 h) {
    union { __hip_bfloat16 b; unsigned short u; } c; c.b = h; return c.u;
}

// fp32 -> hi/lo bf16 pair (two-term split, ~2^-18 rel err)
static __device__ __forceinline__ void split_hilo(float v, short& hi, short& lo) {
    const __hip_bfloat16 h = __float2bfloat16(v);
    hi = (short)bf_bits(h);
    lo = (short)bf_bits(__float2bfloat16(v - __bfloat162float(h)));
}

// 8 contiguous fp32 -> hi/lo bf16 frags
static __device__ __forceinline__ void cvt8_hilo(const float* __restrict__ p,
                                                 v8s& hi, v8s& lo) {
    #pragma unroll
    for (int i = 0; i < 8; ++i) { short h, l; split_hilo(p[i], h, l); hi[i] = h; lo[i] = l; }
}

// ---------------------------------------------------------------------------
// Fused persistent RNN: 128 wgs = 16 groups x 8 members, 256 thr (4 waves).
// Per step: (a) issue emb gather for this t (latency hides under flag-spin),
// (b) spin on peer flags, (c) stage h(t) from L2 exchange -> LDS hi/lo planes
// and emb rows -> LDS hi/lo planes, (d) MFMA: xp (8 k-iters) + h (16 k-iters),
// 3 chains each (hi*hi, hi*lo, lo*hi) into fp32 acc, (e) tanh, split h to
// hi/lo, publish slice + release flag.
// ---------------------------------------------------------------------------
__global__ __launch_bounds__(256, 1) void rnn_fused(
    const int* __restrict__ X,
    const float* __restrict__ emb,
    const float* __restrict__ Whh,
    const float* __restrict__ Whh_b,
    const float* __restrict__ Wxh,
    const float* __restrict__ Wxh_b,
    unsigned int* __restrict__ ex,
    int* __restrict__ flags,
    float* __restrict__ out)
{
    const int bid  = blockIdx.x;
    const int g    = bid & 15;    // group (bid%8 XCD heuristic: members share XCD)
    const int j    = bid >> 4;    // member 0..7
    const int tid  = threadIdx.x;
    const int w    = tid >> 6;
    const int l    = tid & 63;
    const int lo16 = l & 15;
    const int q    = l >> 4;
    const int cbase = j * 64 + w * 16;   // this wave's 16 output cols
    const int nbase = g * 16;            // this group's 16 batch rows

    // LDS: h hi/lo planes (stride 520: +8 pad, 2-way bank alias = free) and
    // emb hi/lo planes (stride 264). Total 50,176 B.
    __shared__ short hb[2][16][520];
    __shared__ short ebh[16][264];
    __shared__ short ebl[16][264];

    // Preload Whh (fp32) as hi/lo bf16 B-frags: lane lo16 -> col cbase+lo16.
    v8s bhi[16], blo[16];
    {
        const float* wp = Whh + (long)(cbase + lo16) * HID + q * 8;
        #pragma unroll
        for (int kk = 0; kk < 16; ++kk) cvt8_hilo(wp + kk * 32, bhi[kk], blo[kk]);
    }
    // Preload Wxh (fp32, K=256) as hi/lo bf16 B-frags for the xp on-the-fly GEMM.
    v8s xhi[8], xlo[8];
    {
        const float* wp = Wxh + (long)(cbase + lo16) * EMB_D + q * 8;
        #pragma unroll
        for (int kk = 0; kk < 8; ++kk) cvt8_hilo(wp + kk * 32, xhi[kk], xlo[kk]);
    }
    const int hcol = cbase + lo16;
    const float bias = Whh_b[hcol] + Wxh_b[hcol];

    // emb gather geometry: thread (u = tid>>4, c = tid&15) covers emb row of
    // batch row nbase+u, elements c*16 .. c*16+15.
    const int gu = tid >> 4, gc = tid & 15;
    const long xrowbase = (long)(nbase + gu) * L_SEQ;

    int* myflags = flags + g * GWGS * FLAG_STRIDE;

    for (int t = 0; t < L_SEQ; ++t) {
        // (a) issue emb gather for step t NOW — in flight during the spin.
        float4 e0, e1, e2, e3;
        {
            const int idx = X[xrowbase + t];
            const float* ep = emb + (long)idx * EMB_D + gc * 16;
            e0 = *(const float4*)(ep + 0);
            e1 = *(const float4*)(ep + 4);
            e2 = *(const float4*)(ep + 8);
            e3 = *(const float4*)(ep + 12);
        }

        // (b) wait for all members to have published h(t)
        if (tid < GWGS) {
            while (__hip_atomic_load(&myflags[tid * FLAG_STRIDE],
                                     __ATOMIC_ACQUIRE, __HIP_MEMORY_SCOPE_AGENT) < t) {}
        }
        __syncthreads();   // also: prev step's MFMA reads done -> LDS reusable

        // (c1) stage h(t) (packed hi|lo<<16) -> LDS planes, coalesced.
        {
            const unsigned long long* exsrc = (const unsigned long long*)
                (ex + (size_t)((t & 1) * NGROUPS + g) * EX_WORDS_PER_GROUP);
            #pragma unroll
            for (int u = 0; u < 16; ++u) {
                unsigned long long v = __hip_atomic_load(exsrc + u * 256 + tid,
                                        __ATOMIC_RELAXED, __HIP_MEMORY_SCOPE_AGENT);
                const unsigned int w0 = (unsigned int)v;
                const unsigned int w1 = (unsigned int)(v >> 32);
                const int k = 2 * tid;
                *(unsigned int*)&hb[0][u][k] = (w0 & 0xffffu) | (w1 << 16);
                *(unsigned int*)&hb[1][u][k] = (w0 >> 16)    | (w1 & 0xffff0000u);
            }
        }
        // (c2) convert gathered emb row chunk -> LDS hi/lo planes (16 shorts each)
        {
            short* hp = &ebh[gu][gc * 16];
            short* lp = &ebl[gu][gc * 16];
            const float ev[16] = {e0.x,e0.y,e0.z,e0.w, e1.x,e1.y,e1.z,e1.w,
                                  e2.x,e2.y,e2.z,e2.w, e3.x,e3.y,e3.z,e3.w};
            #pragma unroll
            for (int i = 0; i < 16; ++i) { short h, lo; split_hilo(ev[i], h, lo); hp[i] = h; lp[i] = lo; }
        }
        __syncthreads();

        // (d) MFMA into fp32 acc: xp first (K=256), then h (K=512)
        v4f acc0 = {0,0,0,0}, acc1 = {0,0,0,0}, acc2 = {0,0,0,0};
        #pragma unroll
        for (int kk = 0; kk < 8; ++kk) {
            v8s ah = *(const v8s*)&ebh[lo16][kk * 32 + q * 8];
            v8s al = *(const v8s*)&ebl[lo16][kk * 32 + q * 8];
            acc0 = __builtin_amdgcn_mfma_f32_16x16x32_bf16(ah, xhi[kk], acc0, 0, 0, 0);
            acc1 = __builtin_amdgcn_mfma_f32_16x16x32_bf16(ah, xlo[kk], acc1, 0, 0, 0);
            acc2 = __builtin_amdgcn_mfma_f32_16x16x32_bf16(al, xhi[kk], acc2, 0, 0, 0);
        }
        #pragma unroll
        for (int kk = 0; kk < 16; ++kk) {
            v8s ah = *(const v8s*)&hb[0][lo16][kk * 32 + q * 8];
            v8s al = *(const v8s*)&hb[1][lo16][kk * 32 + q * 8];
            acc0 = __builtin_amdgcn_mfma_f32_16x16x32_bf16(ah, bhi[kk], acc0, 0, 0, 0);
            acc1 = __builtin_amdgcn_mfma_f32_16x16x32_bf16(ah, blo[kk], acc1, 0, 0, 0);
            acc2 = __builtin_amdgcn_mfma_f32_16x16x32_bf16(al, bhi[kk], acc2, 0, 0, 0);
        }

        // (e) epilogue: tanh, split hi/lo, publish slice + flag
        unsigned int* exdst = ex + (size_t)(((t + 1) & 1) * NGROUPS + g) * EX_WORDS_PER_GROUP;
        #pragma unroll
        for (int r = 0; r < 4; ++r) {
            const int mloc = q * 4 + r;             // C/D: row = (lane>>4)*4 + r
            const int mrow = nbase + mloc;
            const float pre = acc0[r] + acc1[r] + acc2[r] + bias;
            const float hv = tanhf(pre);
            if (t < L_SEQ - 1) {
                short hi, lo; split_hilo(hv, hi, lo);
                const unsigned int word = (unsigned int)(unsigned short)hi
                                        | ((unsigned int)(unsigned short)lo << 16);
                __hip_atomic_store(&exdst[mloc * HID + hcol], word,
                                   __ATOMIC_RELAXED, __HIP_MEMORY_SCOPE_AGENT);
            } else {
                out[(long)mrow * HID + hcol] = hv;   // fp32 output
            }
        }
        if (t < L_SEQ - 1) {
            __syncthreads();  // drains vmcnt(0) per wave: slice stores coherent
            if (tid == 0)
                __hip_atomic_store(&myflags[j * FLAG_STRIDE], t + 1,
                                   __ATOMIC_RELEASE, __HIP_MEMORY_SCOPE_AGENT);
        }
    }
}

// ---------------------------------------------------------------------------
extern "C" void kernel_launch(void* const* d_in, const int* in_sizes, int n_in,
                              void* d_out, int out_size, void* d_ws, size_t ws_size,
                              hipStream_t stream) {
    const int*   X     = (const int*)d_in[0];
    const float* emb   = (const float*)d_in[1];
    const float* Whh   = (const float*)d_in[2];
    const float* Whh_b = (const float*)d_in[3];
    const float* Wxh   = (const float*)d_in[4];
    const float* Wxh_b = (const float*)d_in[5];

    char* ws = (char*)d_ws;
    unsigned int* ex    = (unsigned int*)ws;
    int*          flags = (int*)(ws + EX_BYTES);

    // ws is re-poisoned to 0xAA before every timed launch: zero exchange
    // buffers (h(0) = 0) and flags every call.
    hipMemsetAsync(ex, 0, EX_BYTES + FLAG_BYTES, stream);

    rnn_fused<<<dim3(NGROUPS * GWGS), dim3(256), 0, stream>>>(
        X, emb, Whh, Whh_b, Wxh, Wxh_b, ex, flags, (float*)d_out);
}

// Round 5
// 3233.788 us; speedup vs baseline: 1.2594x; 1.2594x over previous
//
#include <hip/hip_runtime.h>
#include <hip/hip_bf16.h>
#include <math.h>

// Problem constants
#define N_B    256   // batch
#define L_SEQ  512   // sequence length
#define HID    512   // hidden
#define EMB_D  256   // embedding dim

// Decomposition: 16 groups x 16 batch rows; 8 wgs per group, each owns a
// 64-col slice of Whh (hi/lo bf16 in registers) AND the matching 64-col slice
// of Wxh. xp_t computed on the fly (no XP workspace; ws can't hold 268 MB).
#define NGROUPS 16
#define GWGS    8
#define FLAG_STRIDE 16   // ints; 64B per flag to avoid line sharing

// Workspace layout (bytes): exchange + flags only (~1.1 MB)
#define EX_WORDS_PER_GROUP (16 * HID)                        // 8192 uints = 32KB
#define EX_BYTES  ((size_t)2 * NGROUPS * EX_WORDS_PER_GROUP * 4)  // 1 MB (dbuf)
#define FLAG_BYTES ((size_t)NGROUPS * GWGS * FLAG_STRIDE * 4)

typedef short v8s __attribute__((ext_vector_type(8)));   // 8 bf16 MFMA A/B frag
typedef float v4f __attribute__((ext_vector_type(4)));   // MFMA C/D frag

static __device__ __forceinline__ unsigned short bf_bits(__hip_bfloat16 h) {
    union { __hip_bfloat16 b; unsigned short u; } c; c.b = h; return c.u;
}

// fp32 -> hi/lo bf16 pair (two-term split, ~2^-18 rel err)
static __device__ __forceinline__ void split_hilo(float v, short& hi, short& lo) {
    const __hip_bfloat16 h = __float2bfloat16(v);
    hi = (short)bf_bits(h);
    lo = (short)bf_bits(__float2bfloat16(v - __bfloat162float(h)));
}

// 8 contiguous fp32 -> hi/lo bf16 frags
static __device__ __forceinline__ void cvt8_hilo(const float* __restrict__ p,
                                                 v8s& hi, v8s& lo) {
    #pragma unroll
    for (int i = 0; i < 8; ++i) { short h, l; split_hilo(p[i], h, l); hi[i] = h; lo[i] = l; }
}

// ---------------------------------------------------------------------------
// Fused persistent RNN: 128 wgs = 16 groups x 8 members, 256 thr (4 waves).
// Protocol: ALL exchange/flag ops are RELAXED agent-scope atomics -> plain
// global_load/store with sc1 (coherent at L3), NO buffer_inv / buffer_wbl2.
// R4's ACQUIRE spin emitted buffer_inv per poll (L2-invalidate storm -> 198MB
// HBM refetch of emb) and the RELEASE emitted buffer_wbl2 per step: 7.85us/step.
// Ordering: producer drains stores via __syncthreads (vmcnt(0) before
// s_barrier), then relaxed flag store; consumer observes flag (sc1 read of the
// coherence point), barrier, then sc1 data loads -> data is already at L3.
// xp MFMA block runs BEFORE the spin (independent of peers) to hide compute
// in the wait; emb gather for t+1 is software-pipelined.
// ---------------------------------------------------------------------------
__global__ __launch_bounds__(256, 1) void rnn_fused(
    const int* __restrict__ X,
    const float* __restrict__ emb,
    const float* __restrict__ Whh,
    const float* __restrict__ Whh_b,
    const float* __restrict__ Wxh,
    const float* __restrict__ Wxh_b,
    unsigned int* __restrict__ ex,
    int* __restrict__ flags,
    float* __restrict__ out)
{
    const int bid  = blockIdx.x;
    const int g    = bid & 15;    // group
    const int j    = bid >> 4;    // member 0..7
    const int tid  = threadIdx.x;
    const int w    = tid >> 6;
    const int l    = tid & 63;
    const int lo16 = l & 15;
    const int q    = l >> 4;
    const int cbase = j * 64 + w * 16;   // this wave's 16 output cols
    const int nbase = g * 16;            // this group's 16 batch rows

    // LDS: h hi/lo planes (stride 520) + emb hi/lo planes (stride 264) = 50,176 B
    __shared__ short hb[2][16][520];
    __shared__ short ebh[16][264];
    __shared__ short ebl[16][264];

    // Preload Whh (fp32) as hi/lo bf16 B-frags: lane lo16 -> col cbase+lo16.
    v8s bhi[16], blo[16];
    {
        const float* wp = Whh + (long)(cbase + lo16) * HID + q * 8;
        #pragma unroll
        for (int kk = 0; kk < 16; ++kk) cvt8_hilo(wp + kk * 32, bhi[kk], blo[kk]);
    }
    // Preload Wxh (fp32, K=256) as hi/lo bf16 B-frags.
    v8s xhi[8], xlo[8];
    {
        const float* wp = Wxh + (long)(cbase + lo16) * EMB_D + q * 8;
        #pragma unroll
        for (int kk = 0; kk < 8; ++kk) cvt8_hilo(wp + kk * 32, xhi[kk], xlo[kk]);
    }
    const int hcol = cbase + lo16;
    const float bias = Whh_b[hcol] + Wxh_b[hcol];

    // emb gather geometry: thread (u = tid>>4, c = tid&15) covers batch row
    // nbase+u, elements c*16 .. c*16+15.
    const int gu = tid >> 4, gc = tid & 15;
    const long xrowbase = (long)(nbase + gu) * L_SEQ;

    int* myflags = flags + g * GWGS * FLAG_STRIDE;

    // Pipelined emb gather for t=0
    float4 e0, e1, e2, e3;
    {
        const int idx = X[xrowbase + 0];
        const float* ep = emb + (long)idx * EMB_D + gc * 16;
        e0 = *(const float4*)(ep + 0);  e1 = *(const float4*)(ep + 4);
        e2 = *(const float4*)(ep + 8);  e3 = *(const float4*)(ep + 12);
    }

    for (int t = 0; t < L_SEQ; ++t) {
        // (a) stage emb(t) -> LDS hi/lo planes
        {
            short* hp = &ebh[gu][gc * 16];
            short* lp = &ebl[gu][gc * 16];
            const float ev[16] = {e0.x,e0.y,e0.z,e0.w, e1.x,e1.y,e1.z,e1.w,
                                  e2.x,e2.y,e2.z,e2.w, e3.x,e3.y,e3.z,e3.w};
            #pragma unroll
            for (int i = 0; i < 16; ++i) { short h, lo; split_hilo(ev[i], h, lo); hp[i] = h; lp[i] = lo; }
        }
        // (b) issue emb gather for t+1 (latency hidden behind this step)
        if (t + 1 < L_SEQ) {
            const int idx = X[xrowbase + t + 1];
            const float* ep = emb + (long)idx * EMB_D + gc * 16;
            e0 = *(const float4*)(ep + 0);  e1 = *(const float4*)(ep + 4);
            e2 = *(const float4*)(ep + 8);  e3 = *(const float4*)(ep + 12);
        }
        __syncthreads();   // emb staged (also: prev step's LDS reads all drained)

        // (c) xp MFMA (independent of peers) — hides compute in the wait
        v4f acc0 = {0,0,0,0}, acc1 = {0,0,0,0}, acc2 = {0,0,0,0};
        #pragma unroll
        for (int kk = 0; kk < 8; ++kk) {
            v8s ah = *(const v8s*)&ebh[lo16][kk * 32 + q * 8];
            v8s al = *(const v8s*)&ebl[lo16][kk * 32 + q * 8];
            acc0 = __builtin_amdgcn_mfma_f32_16x16x32_bf16(ah, xhi[kk], acc0, 0, 0, 0);
            acc1 = __builtin_amdgcn_mfma_f32_16x16x32_bf16(ah, xlo[kk], acc1, 0, 0, 0);
            acc2 = __builtin_amdgcn_mfma_f32_16x16x32_bf16(al, xhi[kk], acc2, 0, 0, 0);
        }

        // (d) spin: RELAXED loads only (global_load sc1, NO buffer_inv)
        if (tid < GWGS) {
            while (__hip_atomic_load(&myflags[tid * FLAG_STRIDE],
                                     __ATOMIC_RELAXED, __HIP_MEMORY_SCOPE_AGENT) < t) {}
        }
        __syncthreads();

        // (e) stage h(t) (packed hi|lo<<16, sc1 reads of L3) -> LDS planes
        {
            const unsigned long long* exsrc = (const unsigned long long*)
                (ex + (size_t)((t & 1) * NGROUPS + g) * EX_WORDS_PER_GROUP);
            #pragma unroll
            for (int u = 0; u < 16; ++u) {
                unsigned long long v = __hip_atomic_load(exsrc + u * 256 + tid,
                                        __ATOMIC_RELAXED, __HIP_MEMORY_SCOPE_AGENT);
                const unsigned int w0 = (unsigned int)v;
                const unsigned int w1 = (unsigned int)(v >> 32);
                const int k = 2 * tid;
                *(unsigned int*)&hb[0][u][k] = (w0 & 0xffffu) | (w1 << 16);
                *(unsigned int*)&hb[1][u][k] = (w0 >> 16)    | (w1 & 0xffff0000u);
            }
        }
        __syncthreads();

        // (f) h MFMA (K=512), 3 chains into fp32 acc
        #pragma unroll
        for (int kk = 0; kk < 16; ++kk) {
            v8s ah = *(const v8s*)&hb[0][lo16][kk * 32 + q * 8];
            v8s al = *(const v8s*)&hb[1][lo16][kk * 32 + q * 8];
            acc0 = __builtin_amdgcn_mfma_f32_16x16x32_bf16(ah, bhi[kk], acc0, 0, 0, 0);
            acc1 = __builtin_amdgcn_mfma_f32_16x16x32_bf16(ah, blo[kk], acc1, 0, 0, 0);
            acc2 = __builtin_amdgcn_mfma_f32_16x16x32_bf16(al, bhi[kk], acc2, 0, 0, 0);
        }

        // (g) epilogue: tanh, split hi/lo, publish (relaxed sc1 stores)
        unsigned int* exdst = ex + (size_t)(((t + 1) & 1) * NGROUPS + g) * EX_WORDS_PER_GROUP;
        #pragma unroll
        for (int r = 0; r < 4; ++r) {
            const int mloc = q * 4 + r;             // C/D: row = (lane>>4)*4 + r
            const int mrow = nbase + mloc;
            const float pre = acc0[r] + acc1[r] + acc2[r] + bias;
            const float hv = tanhf(pre);
            if (t < L_SEQ - 1) {
                short hi, lo; split_hilo(hv, hi, lo);
                const unsigned int word = (unsigned int)(unsigned short)hi
                                        | ((unsigned int)(unsigned short)lo << 16);
                __hip_atomic_store(&exdst[mloc * HID + hcol], word,
                                   __ATOMIC_RELAXED, __HIP_MEMORY_SCOPE_AGENT);
            } else {
                out[(long)mrow * HID + hcol] = hv;   // fp32 output
            }
        }
        if (t < L_SEQ - 1) {
            // __syncthreads lowers to s_waitcnt vmcnt(0) ... + s_barrier per
            // wave: all sc1 stores acked at the coherence point before the
            // flag store below. No wbl2 needed (stores are write-through).
            __syncthreads();
            if (tid == 0)
                __hip_atomic_store(&myflags[j * FLAG_STRIDE], t + 1,
                                   __ATOMIC_RELAXED, __HIP_MEMORY_SCOPE_AGENT);
        }
    }
}

// ---------------------------------------------------------------------------
extern "C" void kernel_launch(void* const* d_in, const int* in_sizes, int n_in,
                              void* d_out, int out_size, void* d_ws, size_t ws_size,
                              hipStream_t stream) {
    const int*   X     = (const int*)d_in[0];
    const float* emb   = (const float*)d_in[1];
    const float* Whh   = (const float*)d_in[2];
    const float* Whh_b = (const float*)d_in[3];
    const float* Wxh   = (const float*)d_in[4];
    const float* Wxh_b = (const float*)d_in[5];

    char* ws = (char*)d_ws;
    unsigned int* ex    = (unsigned int*)ws;
    int*          flags = (int*)(ws + EX_BYTES);

    // ws re-poisoned to 0xAA before every timed launch: zero exchange + flags
    // every call (memset kernel's end-of-kernel release flushes to coherence
    // point, so sc1 readers see the zeros).
    hipMemsetAsync(ex, 0, EX_BYTES + FLAG_BYTES, stream);

    rnn_fused<<<dim3(NGROUPS * GWGS), dim3(256), 0, stream>>>(
        X, emb, Whh, Whh_b, Wxh, Wxh_b, ex, flags, (float*)d_out);
}

// Round 6
// 2968.152 us; speedup vs baseline: 1.3721x; 1.0895x over previous
//
#include <hip/hip_runtime.h>
#include <hip/hip_bf16.h>
#include <math.h>

// Problem constants
#define N_B    256   // batch
#define L_SEQ  512   // sequence length
#define HID    512   // hidden
#define EMB_D  256   // embedding dim

// 16 groups x 16 batch rows; 8 wgs/group each owning 64 Whh cols (hi/lo bf16
// in registers). Per-wave flags: 8 members x 4 waves = 32 flags/group.
#define NGROUPS 16
#define GWGS    8
#define NFLAGS  32
#define FLAG_STRIDE 16   // ints; 64 B per flag

// Workspace: E_sw (pre-gathered/split/swizzled emb@A-frag order) + exchange + flags
#define ESW_SHORTS_PER_BLK 8192   // per (g,t): 2 planes x 8 kk x 64 lanes x 8 = 16 KB
#define ESW_BYTES  ((size_t)NGROUPS * L_SEQ * ESW_SHORTS_PER_BLK * 2)  // 134,217,728
#define EX_UINTS_PER_SLOT (16 * HID)                                   // 8192 = 32 KB
#define EX_BYTES   ((size_t)2 * NGROUPS * EX_UINTS_PER_SLOT * 4)       // 1 MB
#define FLAG_BYTES ((size_t)NGROUPS * NFLAGS * FLAG_STRIDE * 4)        // 32 KB

typedef short v8s __attribute__((ext_vector_type(8)));   // 8 bf16 MFMA A/B frag
typedef float v4f __attribute__((ext_vector_type(4)));   // MFMA C/D frag

static __device__ __forceinline__ unsigned short bf_bits(__hip_bfloat16 h) {
    union { __hip_bfloat16 b; unsigned short u; } c; c.b = h; return c.u;
}
static __device__ __forceinline__ void split_hilo(float v, short& hi, short& lo) {
    const __hip_bfloat16 h = __float2bfloat16(v);
    hi = (short)bf_bits(h);
    lo = (short)bf_bits(__float2bfloat16(v - __bfloat162float(h)));
}
static __device__ __forceinline__ void cvt8_hilo(const float* __restrict__ p,
                                                 v8s& hi, v8s& lo) {
    #pragma unroll
    for (int i = 0; i < 8; ++i) { short h, l; split_hilo(p[i], h, l); hi[i] = h; lo[i] = l; }
}
// async global->LDS, 16 B per lane; LDS dest = wave-uniform base + lane*16
static __device__ __forceinline__ void gl_lds16(const short* g, short* l) {
    __builtin_amdgcn_global_load_lds(
        (const __attribute__((address_space(1))) unsigned int*)g,
        (__attribute__((address_space(3))) unsigned int*)l, 16, 0, 0);
}
// fast tanh: 1 - 2/(exp(2x)+1); v_exp_f32-based, ~1e-7 abs err
static __device__ __forceinline__ float tanh_fast(float x) {
    const float z = __expf(2.0f * x);
    return 1.0f - 2.0f / (z + 1.0f);
}

// ---------------------------------------------------------------------------
// Precompute E_sw: for each (g,t): 16 emb rows (batch rows g*16..+15) split to
// hi/lo bf16 and laid out in MFMA A-frag order:
//   short off = plane*4096 + (kk*64 + lane)*8 + i,  lane = m + 16*q',
//   element = emb[X[g*16+m][t]][kk*32 + q'*8 + i]
// ---------------------------------------------------------------------------
__global__ __launch_bounds__(256) void esw_build(
    const int* __restrict__ X, const float* __restrict__ emb,
    short* __restrict__ Esw)
{
    const int bid = blockIdx.x;           // g*512 + t
    const int g = bid >> 9, t = bid & 511;
    short* base = Esw + (size_t)bid * ESW_SHORTS_PER_BLK;
    #pragma unroll
    for (int h = 0; h < 2; ++h) {
        const int f    = threadIdx.x + h * 256;   // frag id 0..511
        const int kk   = f >> 6, lane = f & 63;
        const int m    = lane & 15, qp = lane >> 4;
        const int idx  = X[(g * 16 + m) * L_SEQ + t];
        const float* src = emb + (size_t)idx * EMB_D + kk * 32 + qp * 8;
        v8s hi8, lo8;
        cvt8_hilo(src, hi8, lo8);
        short* d = base + (size_t)(kk * 64 + lane) * 8;
        *(v8s*)d          = hi8;
        *(v8s*)(d + 4096) = lo8;
    }
}

// ---------------------------------------------------------------------------
// Persistent RNN scan. 128 wgs = 16 groups x 8 members, 256 thr (4 waves).
// Exchange (global, per group, parity-dbuf) holds h(t) as packed hi|lo<<16
// uints in A-frag order: off = (kk*64 + lane)*8 + i.
// Per step: [issue E stage via global_load_lds] -> [spin 32 wave-flags >= t]
// -> [stage h: 16 u64 sc1 loads + unpack -> LDS planes] -> ONE barrier ->
// [72 MFMA from ds_read_b128 frags] -> [tanh, split, scatter-publish,
// s_waitcnt vmcnt(0), per-wave flag store]. No other barriers: parity dbuf +
// the spin guarantee (flag=t => that wave finished step t-1 reads) kill WAR.
// ---------------------------------------------------------------------------
__global__ __launch_bounds__(256, 1) void rnn_scan2(
    const float* __restrict__ Whh,
    const float* __restrict__ Whh_b,
    const float* __restrict__ Wxh,
    const float* __restrict__ Wxh_b,
    const short* __restrict__ Esw,
    unsigned int* __restrict__ ex,
    int* __restrict__ flags,
    float* __restrict__ out)
{
    const int bid  = blockIdx.x;
    const int g    = bid & 15;    // group (members g,16+g,..,112+g -> same XCD via %8)
    const int j    = bid >> 4;    // member 0..7
    const int tid  = threadIdx.x;
    const int w    = tid >> 6;
    const int l    = tid & 63;
    const int lo16 = l & 15;
    const int q    = l >> 4;
    const int cbase = j * 64 + w * 16;
    const int nbase = g * 16;

    // LDS (shorts): h planes dbuf [P][plane][8192] = 64 KB, then E dbuf
    // [P][plane][4096] = 32 KB. Total 96 KB.
    __shared__ short ldsbuf[49152];
    short* lds_h = ldsbuf;          // P*16384 + plane*8192 + (kk*64+l)*8 + i
    short* lds_e = ldsbuf + 32768;  // P*8192  + plane*4096 + (kk*64+l)*8 + i

    // Whh 64-col slice as hi/lo bf16 B-frags (128 VGPRs)
    v8s bhi[16], blo[16];
    {
        const float* wp = Whh + (long)(cbase + lo16) * HID + q * 8;
        #pragma unroll
        for (int kk = 0; kk < 16; ++kk) cvt8_hilo(wp + kk * 32, bhi[kk], blo[kk]);
    }
    // Wxh 64-col slice (64 VGPRs)
    v8s xhi[8], xlo[8];
    {
        const float* wp = Wxh + (long)(cbase + lo16) * EMB_D + q * 8;
        #pragma unroll
        for (int kk = 0; kk < 8; ++kk) cvt8_hilo(wp + kk * 32, xhi[kk], xlo[kk]);
    }
    const int hcol = cbase + lo16;
    const float bias = Whh_b[hcol] + Wxh_b[hcol];

    // epilogue scatter geometry (A-frag coords of column hcol)
    const int kk_s = (hcol >> 5);             // 2j + (w>>1)
    const int q2   = (hcol >> 3) & 3;
    const int i_s  = hcol & 7;

    int* myflags = flags + g * NFLAGS * FLAG_STRIDE;
    int* flp = myflags + (l & 31) * FLAG_STRIDE;   // lane<32 polls flag l
    const int myflag = (j * 4 + w) * FLAG_STRIDE;

    unsigned int* ex0 = ex + (size_t)g * EX_UINTS_PER_SLOT;                 // parity 0
    unsigned int* ex1 = ex + (size_t)(NGROUPS + g) * EX_UINTS_PER_SLOT;     // parity 1
    const short* esrc = Esw + (size_t)(g * 512) * ESW_SHORTS_PER_BLK;

    for (int t = 0; t < L_SEQ; ++t) {
        const int P = t & 1;
        short* lh = lds_h + P * 16384;
        short* le = lds_e + P * 8192;
        unsigned int* exsrc = P ? ex1 : ex0;
        unsigned int* exdst = P ? ex0 : ex1;

        // (1) issue E stage for t (async, independent of peers): wave stages
        //     4 KB of the 16 KB block; flat copy (A-frag order matches LDS).
        {
            const short* eb = esrc + (size_t)t * ESW_SHORTS_PER_BLK;
            #pragma unroll
            for (int c = 0; c < 4; ++c) {
                const int seg = w * 4 + c;                 // 0..15 x 1 KB
                gl_lds16(eb + seg * 512 + l * 8, le + seg * 512);
            }
        }

        // (2) spin: all 32 wave-flags >= t (relaxed sc1 loads, no cache maint)
        {
            int ok;
            do {
                int fl = 0x7fffffff;
                if (l < 32) fl = __hip_atomic_load(flp, __ATOMIC_RELAXED,
                                                   __HIP_MEMORY_SCOPE_AGENT);
                ok = __all((l >= 32) | (fl >= t));
            } while (!ok);
        }

        // (3) stage h: thread copies 128 B (16 u64) of the 32 KB slot; unpack
        //     packed hi|lo<<16 pairs into separate LDS planes (u32 writes).
        {
            const unsigned long long* hs =
                (const unsigned long long*)exsrc + tid * 16;
            unsigned int* lh_hi = (unsigned int*)lh + tid * 16;
            unsigned int* lh_lo = lh_hi + 4096;
            #pragma unroll
            for (int s = 0; s < 16; ++s) {
                unsigned long long v = __hip_atomic_load(hs + s, __ATOMIC_RELAXED,
                                                         __HIP_MEMORY_SCOPE_AGENT);
                const unsigned int w0 = (unsigned int)v;
                const unsigned int w1 = (unsigned int)(v >> 32);
                lh_hi[s] = (w0 & 0xffffu) | (w1 << 16);
                lh_lo[s] = (w0 >> 16)     | (w1 & 0xffff0000u);
            }
        }

        // (4) the step's ONLY barrier: LDS staging (ds + global_load_lds) done
        __syncthreads();

        // (5) MFMA: xp (K=256) + h (K=512), 3 hi/lo chains, fp32 acc
        v4f acc0 = {0,0,0,0}, acc1 = {0,0,0,0}, acc2 = {0,0,0,0};
        #pragma unroll
        for (int kk = 0; kk < 8; ++kk) {
            v8s ah = *(const v8s*)(le + (kk * 64 + l) * 8);
            v8s al = *(const v8s*)(le + 4096 + (kk * 64 + l) * 8);
            acc0 = __builtin_amdgcn_mfma_f32_16x16x32_bf16(ah, xhi[kk], acc0, 0, 0, 0);
            acc1 = __builtin_amdgcn_mfma_f32_16x16x32_bf16(ah, xlo[kk], acc1, 0, 0, 0);
            acc2 = __builtin_amdgcn_mfma_f32_16x16x32_bf16(al, xhi[kk], acc2, 0, 0, 0);
        }
        #pragma unroll
        for (int kk = 0; kk < 16; ++kk) {
            v8s ah = *(const v8s*)(lh + (kk * 64 + l) * 8);
            v8s al = *(const v8s*)(lh + 8192 + (kk * 64 + l) * 8);
            acc0 = __builtin_amdgcn_mfma_f32_16x16x32_bf16(ah, bhi[kk], acc0, 0, 0, 0);
            acc1 = __builtin_amdgcn_mfma_f32_16x16x32_bf16(ah, blo[kk], acc1, 0, 0, 0);
            acc2 = __builtin_amdgcn_mfma_f32_16x16x32_bf16(al, bhi[kk], acc2, 0, 0, 0);
        }

        // (6) epilogue: tanh, split, publish into A-frag slots of parity t+1
        #pragma unroll
        for (int r = 0; r < 4; ++r) {
            const int m = q * 4 + r;                 // C/D: row=(lane>>4)*4+r
            const float pre = acc0[r] + acc1[r] + acc2[r] + bias;
            const float hv = tanh_fast(pre);
            if (t < L_SEQ - 1) {
                short hi, lo; split_hilo(hv, hi, lo);
                const unsigned int word = (unsigned int)(unsigned short)hi
                                        | ((unsigned int)(unsigned short)lo << 16);
                const int lane2 = m + 16 * q2;
                __hip_atomic_store(exdst + (kk_s * 64 + lane2) * 8 + i_s, word,
                                   __ATOMIC_RELAXED, __HIP_MEMORY_SCOPE_AGENT);
            } else {
                out[(long)(nbase + m) * HID + hcol] = hv;
            }
        }
        // (7) drain own stores, publish own wave flag (no barrier)
        if (t < L_SEQ - 1) {
            asm volatile("s_waitcnt vmcnt(0)" ::: "memory");
            if (l == 0)
                __hip_atomic_store(myflags + myflag, t + 1,
                                   __ATOMIC_RELAXED, __HIP_MEMORY_SCOPE_AGENT);
        }
    }
}

// ---------------------------------------------------------------------------
extern "C" void kernel_launch(void* const* d_in, const int* in_sizes, int n_in,
                              void* d_out, int out_size, void* d_ws, size_t ws_size,
                              hipStream_t stream) {
    const int*   X     = (const int*)d_in[0];
    const float* emb   = (const float*)d_in[1];
    const float* Whh   = (const float*)d_in[2];
    const float* Whh_b = (const float*)d_in[3];
    const float* Wxh   = (const float*)d_in[4];
    const float* Wxh_b = (const float*)d_in[5];

    char* ws = (char*)d_ws;
    short*        Esw   = (short*)ws;
    unsigned int* ex    = (unsigned int*)(ws + ESW_BYTES);
    int*          flags = (int*)(ws + ESW_BYTES + EX_BYTES);

    // ws re-poisoned to 0xAA each timed launch: zero exchange (h(0)=0) + flags.
    hipMemsetAsync(ex, 0, EX_BYTES + FLAG_BYTES, stream);

    esw_build<<<dim3(NGROUPS * L_SEQ), dim3(256), 0, stream>>>(X, emb, Esw);
    rnn_scan2<<<dim3(NGROUPS * GWGS), dim3(256), 0, stream>>>(
        Whh, Whh_b, Wxh, Wxh_b, Esw, ex, flags, (float*)d_out);
}